// Round 7
// baseline (883.961 us; speedup 1.0000x reference)
//
#include <hip/hip_runtime.h>
#include <stdint.h>

#define IN_LEN 4096
#define NFEAT  10000

// ---- workspace byte layout ----
#define WS_CNTA 0      // u32: K1 last-block counter
#define WS_DONE 256    // 256 u32: per-row done counters for K2
#define WS_Q    2048   // 768 f32: per-sample quantiles
#define WS_BIAS 8192   // 3 f32: biases

// cnt += (key <= mid)   -- explicit sgpr carry, mid wave-uniform
__device__ __forceinline__ void count_le_u32(unsigned& cnt, unsigned long long& cc,
                                             unsigned mid, unsigned key) {
  asm("v_cmp_ge_u32 %[cc], %[m], %[k]\n\t"
      "v_addc_co_u32 %[c], %[cc], 0, %[c], %[cc]"
      : [c] "+v"(cnt), [cc] "=&s"(cc)
      : [m] "s"(mid), [k] "v"(key));
}

__device__ __forceinline__ unsigned key_of(float f) {
  unsigned u = __float_as_uint(f);
  return (u & 0x80000000u) ? ~u : (u | 0x80000000u);
}
__device__ __forceinline__ float key_inv(unsigned k) {
  unsigned u = (k & 0x80000000u) ? (k ^ 0x80000000u) : ~k;
  return __uint_as_float(u);
}

// ---------- K1: per-sample quantiles + fused last-block bias mean ----------
__global__ __launch_bounds__(256) void quantbias_kernel(const float* __restrict__ x,
                                                        const float* __restrict__ kern,
                                                        unsigned char* __restrict__ ws) {
  const int b = blockIdx.x, tid = threadIdx.x;
  float* ws_q = (float*)(ws + WS_Q);
  float* ws_bias = (float*)(ws + WS_BIAS);
  unsigned* cntA = (unsigned*)(ws + WS_CNTA);

  __shared__ __align__(16) float xs[IN_LEN];
  __shared__ unsigned redc[2][3 * 4];
  __shared__ float redm[256];
  __shared__ unsigned lastflag;

  const float4* xg = (const float4*)(x + (size_t)b * IN_LEN);
  float4* xs4 = (float4*)xs;
  for (int i = tid; i < IN_LEN / 4; i += 256) xs4[i] = xg[i];

  float w[9];
#pragma unroll
  for (int j = 0; j < 9; j++) w[j] = kern[j];
  __syncthreads();

  const int L = IN_LEN - 8;
  unsigned keys[16];
#pragma unroll
  for (int i = 0; i < 16; i++) {
    int t = tid + (i << 8);
    if (t < L) {
      float c = 0.f;
#pragma unroll
      for (int j = 0; j < 9; j++) c = fmaf(w[j], xs[t + j], c);
      keys[i] = key_of(c);
    } else {
      keys[i] = 0xFFFFFFFFu;
    }
  }

  const int targ[6] = {1021, 1022, 2043, 2044, 3065, 3066};
  unsigned lo[6], hi[6];
#pragma unroll
  for (int q = 0; q < 6; q++) { lo[q] = 0u; hi[q] = 0xFFFFFFFFu; }

  const int wave = tid >> 6, lane = tid & 63;
  for (int it = 0; it < 32; ++it) {
    const int buf = it & 1;
    unsigned mid[6], cnt[6];
    unsigned long long ccq[3];
#pragma unroll
    for (int q = 0; q < 6; q++) { mid[q] = lo[q] + ((hi[q] - lo[q]) >> 1); cnt[q] = 0u; }
#pragma unroll
    for (int i = 0; i < 16; i++)
#pragma unroll
      for (int q = 0; q < 6; q++) count_le_u32(cnt[q], ccq[q >> 1], mid[q], keys[i]);
    unsigned r[3];
#pragma unroll
    for (int q = 0; q < 3; q++) r[q] = cnt[2 * q] | (cnt[2 * q + 1] << 16);
#pragma unroll
    for (int q = 0; q < 3; q++) {
#pragma unroll
      for (int off = 32; off > 0; off >>= 1) r[q] += (unsigned)__shfl_xor((int)r[q], off);
    }
    if (lane == 0) {
#pragma unroll
      for (int q = 0; q < 3; q++) redc[buf][q * 4 + wave] = r[q];
    }
    __syncthreads();
#pragma unroll
    for (int q = 0; q < 3; q++) {
      unsigned tot = redc[buf][q * 4 + 0] + redc[buf][q * 4 + 1] +
                     redc[buf][q * 4 + 2] + redc[buf][q * 4 + 3];
      unsigned t0 = tot & 0xFFFFu, t1 = tot >> 16;
      if (t0 >= (unsigned)(targ[2 * q] + 1)) hi[2 * q] = mid[2 * q]; else lo[2 * q] = mid[2 * q] + 1;
      if (t1 >= (unsigned)(targ[2 * q + 1] + 1)) hi[2 * q + 1] = mid[2 * q + 1]; else lo[2 * q + 1] = mid[2 * q + 1] + 1;
    }
  }

  if (tid == 0) {
    float v[6];
#pragma unroll
    for (int q = 0; q < 6; q++) v[q] = key_inv(lo[q]);
    ws_q[b * 3 + 0] = v[0] + 0.75f * (v[1] - v[0]);
    ws_q[b * 3 + 1] = v[2] + 0.5f  * (v[3] - v[2]);
    ws_q[b * 3 + 2] = v[4] + 0.25f * (v[5] - v[4]);
  }

  // ---- publish, last block computes the bias means ----
  __syncthreads();
  if (tid == 0) {
    __threadfence();
    unsigned old = __hip_atomic_fetch_add(cntA, 1u, __ATOMIC_ACQ_REL, __HIP_MEMORY_SCOPE_AGENT);
    lastflag = (old == gridDim.x - 1) ? 1u : 0u;
  }
  __syncthreads();
  if (lastflag == 0u) return;
  __threadfence();
  const int B = gridDim.x;
  for (int q = 0; q < 3; q++) {
    float v = 0.f;
    for (int i = tid; i < B; i += 256) v += ws_q[i * 3 + q];
    redm[tid] = v;
    __syncthreads();
    for (int s = 128; s > 0; s >>= 1) {
      if (tid < s) redm[tid] += redm[tid + s];
      __syncthreads();
    }
    if (tid == 0) ws_bias[q] = redm[0] / (float)B;
    __syncthreads();
  }
}

// ---------- K2: features (sign-collect counting) + fused last-block row norm ----
template <int D>
__device__ __forceinline__ void run_feat(const float* xs,
                                         const float* __restrict__ kern,
                                         float b0, float b1, float b2,
                                         float* __restrict__ row, int K) {
  const int tid = threadIdx.x;
  const int wave = tid >> 6, lane = tid & 63;
  constexpr int L = IN_LEN - 8 * D;
  constexpr int KT = 6;

  const int KPW = (K + 3) >> 2;
  const int kstart = wave * KPW;
  const int kend = (kstart + KPW < K) ? (kstart + KPW) : K;

  for (int k0 = kstart; k0 < kend; k0 += KT) {
    float w[KT][9];
#pragma unroll
    for (int kk = 0; kk < KT; kk++) {
      const int kidx = (k0 + kk < K) ? (k0 + kk) : (K - 1);
      const bool ok = (k0 + kk) < kend;
      const float* wp = kern + (size_t)kidx * 9;
#pragma unroll
      for (int j = 0; j < 9; j++) w[kk][j] = ok ? wp[j] : 0.f;
    }
    unsigned c0[KT], c1[KT], c2[KT];   // flushed counters
    unsigned m0[KT], m1[KT], m2[KT];   // sign-bit collectors (2 bits/pass)
#pragma unroll
    for (int kk = 0; kk < KT; kk++) {
      c0[kk] = 0u; c1[kk] = 0u; c2[kk] = 0u;
      m0[kk] = 0u; m1[kk] = 0u; m2[kk] = 0u;
    }

    // ---- segment A: passes 0..15 (32 bits per mask) ----
#pragma unroll 1
    for (int p = 0; p < 16; ++p) {
      const int t = (p << 7) + lane;
      float tax[9], tay[9];
#pragma unroll
      for (int j = 0; j < 9; j++) { tax[j] = xs[t + j * D]; tay[j] = xs[t + 64 + j * D]; }
#pragma unroll
      for (int kk = 0; kk < KT; kk++) {
        float ca = 0.f, cb = 0.f;
#pragma unroll
        for (int j = 0; j < 9; j++) {
          ca = fmaf(w[kk][j], tax[j], ca);
          cb = fmaf(w[kk][j], tay[j], cb);
        }
        m0[kk] = __builtin_amdgcn_alignbit(m0[kk], __float_as_uint(b0 - ca), 31);
        m0[kk] = __builtin_amdgcn_alignbit(m0[kk], __float_as_uint(b0 - cb), 31);
        m1[kk] = __builtin_amdgcn_alignbit(m1[kk], __float_as_uint(b1 - ca), 31);
        m1[kk] = __builtin_amdgcn_alignbit(m1[kk], __float_as_uint(b1 - cb), 31);
        m2[kk] = __builtin_amdgcn_alignbit(m2[kk], __float_as_uint(b2 - ca), 31);
        m2[kk] = __builtin_amdgcn_alignbit(m2[kk], __float_as_uint(b2 - cb), 31);
      }
    }
#pragma unroll
    for (int kk = 0; kk < KT; kk++) {  // flush A
      c0[kk] += (unsigned)__popc(m0[kk]); m0[kk] = 0u;
      c1[kk] += (unsigned)__popc(m1[kk]); m1[kk] = 0u;
      c2[kk] += (unsigned)__popc(m2[kk]); m2[kk] = 0u;
    }

    // ---- segment B: passes 16..30 (30 bits) + tail (2 bits) ----
#pragma unroll 1
    for (int p = 16; p < 31; ++p) {
      const int t = (p << 7) + lane;
      float tax[9], tay[9];
#pragma unroll
      for (int j = 0; j < 9; j++) { tax[j] = xs[t + j * D]; tay[j] = xs[t + 64 + j * D]; }
#pragma unroll
      for (int kk = 0; kk < KT; kk++) {
        float ca = 0.f, cb = 0.f;
#pragma unroll
        for (int j = 0; j < 9; j++) {
          ca = fmaf(w[kk][j], tax[j], ca);
          cb = fmaf(w[kk][j], tay[j], cb);
        }
        m0[kk] = __builtin_amdgcn_alignbit(m0[kk], __float_as_uint(b0 - ca), 31);
        m0[kk] = __builtin_amdgcn_alignbit(m0[kk], __float_as_uint(b0 - cb), 31);
        m1[kk] = __builtin_amdgcn_alignbit(m1[kk], __float_as_uint(b1 - ca), 31);
        m1[kk] = __builtin_amdgcn_alignbit(m1[kk], __float_as_uint(b1 - cb), 31);
        m2[kk] = __builtin_amdgcn_alignbit(m2[kk], __float_as_uint(b2 - ca), 31);
        m2[kk] = __builtin_amdgcn_alignbit(m2[kk], __float_as_uint(b2 - cb), 31);
      }
    }
    {  // tail: t=3968+lane always valid (L-3968 >= 80); t+64 masked
      const int t = 3968 + lane;
      const bool v1 = (t + 64) < L;
      float tax[9], tay[9];
#pragma unroll
      for (int j = 0; j < 9; j++) { tax[j] = xs[t + j * D]; tay[j] = xs[t + 64 + j * D]; }
#pragma unroll
      for (int kk = 0; kk < KT; kk++) {
        float ca = 0.f, cb = 0.f;
#pragma unroll
        for (int j = 0; j < 9; j++) {
          ca = fmaf(w[kk][j], tax[j], ca);
          cb = fmaf(w[kk][j], tay[j], cb);
        }
        cb = v1 ? cb : -3.0e38f;   // below all thresholds -> sign(b-cb)=0, not counted
        m0[kk] = __builtin_amdgcn_alignbit(m0[kk], __float_as_uint(b0 - ca), 31);
        m0[kk] = __builtin_amdgcn_alignbit(m0[kk], __float_as_uint(b0 - cb), 31);
        m1[kk] = __builtin_amdgcn_alignbit(m1[kk], __float_as_uint(b1 - ca), 31);
        m1[kk] = __builtin_amdgcn_alignbit(m1[kk], __float_as_uint(b1 - cb), 31);
        m2[kk] = __builtin_amdgcn_alignbit(m2[kk], __float_as_uint(b2 - ca), 31);
        m2[kk] = __builtin_amdgcn_alignbit(m2[kk], __float_as_uint(b2 - cb), 31);
      }
    }
#pragma unroll
    for (int kk = 0; kk < KT; kk++) {  // flush B+tail
      c0[kk] += (unsigned)__popc(m0[kk]);
      c1[kk] += (unsigned)__popc(m1[kk]);
      c2[kk] += (unsigned)__popc(m2[kk]);
    }

    // ---- wave reduction (pack c0|c2: lane cnt <= 64, wave sum <= 4096) ----
#pragma unroll
    for (int kk = 0; kk < KT; kk++) {
      unsigned r0 = c0[kk] | (c2[kk] << 16);
      unsigned r1 = c1[kk];
#pragma unroll
      for (int off = 32; off > 0; off >>= 1) {
        r0 += (unsigned)__shfl_xor((int)r0, off);
        r1 += (unsigned)__shfl_xor((int)r1, off);
      }
      const int k = k0 + kk;
      if (lane == 0 && k < kend) {
        float* o = row + (size_t)k * 18 + (D - 1) * 3;
        o[0] = (float)(r0 & 0xFFFFu) / (float)L;
        o[1] = (float)r1 / (float)L;
        o[2] = (float)(r0 >> 16) / (float)L;
      }
    }
  }
}

__global__ __launch_bounds__(256, 6) void feat_norm_kernel(const float* __restrict__ x,
                                                           const float* __restrict__ kern,
                                                           unsigned char* __restrict__ ws,
                                                           float* __restrict__ out, int K) {
  __shared__ __align__(16) float xs[IN_LEN + 48];
  __shared__ float red[256];
  __shared__ unsigned lastflag;
  const int b = blockIdx.y, tid = threadIdx.x;
  const float* ws_bias = (const float*)(ws + WS_BIAS);
  unsigned* done = (unsigned*)(ws + WS_DONE);

  const float4* xg = (const float4*)(x + (size_t)b * IN_LEN);
  float4* xs4 = (float4*)xs;
  for (int i = tid; i < IN_LEN / 4; i += 256) xs4[i] = xg[i];
  if (tid < 48) xs[IN_LEN + tid] = 0.f;
  const float b0 = ws_bias[0], b1 = ws_bias[1], b2 = ws_bias[2];
  __syncthreads();

  float* row = out + (size_t)b * NFEAT;
  switch (blockIdx.x) {
    case 0: run_feat<1>(xs, kern, b0, b1, b2, row, K); break;
    case 1: run_feat<2>(xs, kern, b0, b1, b2, row, K); break;
    case 2: run_feat<3>(xs, kern, b0, b1, b2, row, K); break;
    case 3: run_feat<4>(xs, kern, b0, b1, b2, row, K); break;
    case 4: run_feat<5>(xs, kern, b0, b1, b2, row, K); break;
    case 5: run_feat<6>(xs, kern, b0, b1, b2, row, K); break;
  }

  // ---- publish this block's features; 6th block of the row normalizes ----
  __syncthreads();
  if (tid == 0) {
    __threadfence();
    unsigned old = __hip_atomic_fetch_add(&done[b], 1u, __ATOMIC_ACQ_REL, __HIP_MEMORY_SCOPE_AGENT);
    lastflag = (old == 5u) ? 1u : 0u;
  }
  __syncthreads();
  if (lastflag == 0u) return;
  __threadfence();

  const int F = K * 18;
  float acc = 0.f;
  for (int i = tid; i < F; i += 256) {
    float v = row[i];
    acc = fmaf(v, v, acc);
  }
  red[tid] = acc;
  __syncthreads();
  for (int s = 128; s > 0; s >>= 1) {
    if (tid < s) red[tid] += red[tid + s];
    __syncthreads();
  }
  const float inv = 1.0f / fmaxf(sqrtf(red[0]), 1e-12f);
  for (int i = tid; i < NFEAT; i += 256) {
    float v = (i < F) ? row[i] * inv : 0.f;
    row[i] = v;
  }
}

extern "C" void kernel_launch(void* const* d_in, const int* in_sizes, int n_in,
                              void* d_out, int out_size, void* d_ws, size_t ws_size,
                              hipStream_t stream) {
  const float* x = (const float*)d_in[0];
  const float* kern = (const float*)d_in[1];
  float* out = (float*)d_out;
  const int B = in_sizes[0] / IN_LEN;  // 256
  const int K = in_sizes[1] / 9;       // ~61 surviving kernels
  unsigned char* ws = (unsigned char*)d_ws;

  // zero the two counter regions (K1 counter + 256 row counters)
  hipMemsetAsync(ws, 0, 2048, stream);
  quantbias_kernel<<<B, 256, 0, stream>>>(x, kern, ws);
  dim3 g(6, B);
  feat_norm_kernel<<<g, 256, 0, stream>>>(x, kern, ws, out, K);
}

// Round 9
// 362.941 us; speedup vs baseline: 2.4356x; 2.4356x over previous
//
#include <hip/hip_runtime.h>
#include <stdint.h>

#define IN_LEN 4096
#define NFEAT  10000

// ---- workspace byte layout ----
#define WS_CNTA 0      // u32: K1 last-block counter
#define WS_DONE 256    // 256 u32: per-row done counters for K2
#define WS_Q    2048   // 768 f32: per-sample quantiles
#define WS_BIAS 8192   // 3 f32: biases

// ---- 2-op count idioms with EXPLICIT sgpr carry (no vcc serialization) ----
// cnt += (a > thr); cnt += (b > thr)   -- thr wave-uniform (SGPR)
__device__ __forceinline__ void count2_gt_f32(unsigned& cnt, unsigned long long& cc,
                                              float thr, float a, float b) {
  asm("v_cmp_lt_f32 %[cc], %[t], %[va]\n\t"
      "v_addc_co_u32 %[c], %[cc], 0, %[c], %[cc]\n\t"
      "v_cmp_lt_f32 %[cc], %[t], %[vb]\n\t"
      "v_addc_co_u32 %[c], %[cc], 0, %[c], %[cc]"
      : [c] "+v"(cnt), [cc] "=&s"(cc)
      : [t] "s"(thr), [va] "v"(a), [vb] "v"(b));
}
// cnt += (key <= mid)   -- mid wave-uniform (SGPR)
__device__ __forceinline__ void count_le_u32(unsigned& cnt, unsigned long long& cc,
                                             unsigned mid, unsigned key) {
  asm("v_cmp_ge_u32 %[cc], %[m], %[k]\n\t"
      "v_addc_co_u32 %[c], %[cc], 0, %[c], %[cc]"
      : [c] "+v"(cnt), [cc] "=&s"(cc)
      : [m] "s"(mid), [k] "v"(key));
}

__device__ __forceinline__ unsigned key_of(float f) {
  unsigned u = __float_as_uint(f);
  return (u & 0x80000000u) ? ~u : (u | 0x80000000u);
}
__device__ __forceinline__ float key_inv(unsigned k) {
  unsigned u = (k & 0x80000000u) ? (k ^ 0x80000000u) : ~k;
  return __uint_as_float(u);
}

// ---------- K1: per-sample quantiles + fused last-block bias mean ----------
__global__ __launch_bounds__(256) void quantbias_kernel(const float* __restrict__ x,
                                                        const float* __restrict__ kern,
                                                        unsigned char* __restrict__ ws) {
  const int b = blockIdx.x, tid = threadIdx.x;
  float* ws_q = (float*)(ws + WS_Q);
  float* ws_bias = (float*)(ws + WS_BIAS);
  unsigned* cntA = (unsigned*)(ws + WS_CNTA);

  __shared__ __align__(16) float xs[IN_LEN];
  __shared__ unsigned redc[2][3 * 4];
  __shared__ float redm[256];
  __shared__ unsigned lastflag;

  const float4* xg = (const float4*)(x + (size_t)b * IN_LEN);
  float4* xs4 = (float4*)xs;
  for (int i = tid; i < IN_LEN / 4; i += 256) xs4[i] = xg[i];

  float w[9];
#pragma unroll
  for (int j = 0; j < 9; j++) w[j] = kern[j];
  __syncthreads();

  const int L = IN_LEN - 8;
  unsigned keys[16];
#pragma unroll
  for (int i = 0; i < 16; i++) {
    int t = tid + (i << 8);
    if (t < L) {
      float c = 0.f;
#pragma unroll
      for (int j = 0; j < 9; j++) c = fmaf(w[j], xs[t + j], c);
      keys[i] = key_of(c);
    } else {
      keys[i] = 0xFFFFFFFFu;
    }
  }

  const int targ[6] = {1021, 1022, 2043, 2044, 3065, 3066};
  unsigned lo[6], hi[6];
#pragma unroll
  for (int q = 0; q < 6; q++) { lo[q] = 0u; hi[q] = 0xFFFFFFFFu; }

  const int wave = tid >> 6, lane = tid & 63;
  for (int it = 0; it < 32; ++it) {
    const int buf = it & 1;
    unsigned mid[6], cnt[6];
    unsigned long long ccq[3];
#pragma unroll
    for (int q = 0; q < 6; q++) { mid[q] = lo[q] + ((hi[q] - lo[q]) >> 1); cnt[q] = 0u; }
#pragma unroll
    for (int i = 0; i < 16; i++)
#pragma unroll
      for (int q = 0; q < 6; q++) count_le_u32(cnt[q], ccq[q >> 1], mid[q], keys[i]);
    unsigned r[3];
#pragma unroll
    for (int q = 0; q < 3; q++) r[q] = cnt[2 * q] | (cnt[2 * q + 1] << 16);
#pragma unroll
    for (int q = 0; q < 3; q++) {
#pragma unroll
      for (int off = 32; off > 0; off >>= 1) r[q] += (unsigned)__shfl_xor((int)r[q], off);
    }
    if (lane == 0) {
#pragma unroll
      for (int q = 0; q < 3; q++) redc[buf][q * 4 + wave] = r[q];
    }
    __syncthreads();
#pragma unroll
    for (int q = 0; q < 3; q++) {
      unsigned tot = redc[buf][q * 4 + 0] + redc[buf][q * 4 + 1] +
                     redc[buf][q * 4 + 2] + redc[buf][q * 4 + 3];
      unsigned t0 = tot & 0xFFFFu, t1 = tot >> 16;
      if (t0 >= (unsigned)(targ[2 * q] + 1)) hi[2 * q] = mid[2 * q]; else lo[2 * q] = mid[2 * q] + 1;
      if (t1 >= (unsigned)(targ[2 * q + 1] + 1)) hi[2 * q + 1] = mid[2 * q + 1]; else lo[2 * q + 1] = mid[2 * q + 1] + 1;
    }
  }

  if (tid == 0) {
    float v[6];
#pragma unroll
    for (int q = 0; q < 6; q++) v[q] = key_inv(lo[q]);
    ws_q[b * 3 + 0] = v[0] + 0.75f * (v[1] - v[0]);
    ws_q[b * 3 + 1] = v[2] + 0.5f  * (v[3] - v[2]);
    ws_q[b * 3 + 2] = v[4] + 0.25f * (v[5] - v[4]);
  }

  // ---- publish, last block computes the bias means ----
  __syncthreads();
  if (tid == 0) {
    __threadfence();
    unsigned old = __hip_atomic_fetch_add(cntA, 1u, __ATOMIC_ACQ_REL, __HIP_MEMORY_SCOPE_AGENT);
    lastflag = (old == gridDim.x - 1) ? 1u : 0u;
  }
  __syncthreads();
  if (lastflag == 0u) return;
  __threadfence();
  const int B = gridDim.x;
  for (int q = 0; q < 3; q++) {
    float v = 0.f;
    for (int i = tid; i < B; i += 256) v += ws_q[i * 3 + q];
    redm[tid] = v;
    __syncthreads();
    for (int s = 128; s > 0; s >>= 1) {
      if (tid < s) redm[tid] += redm[tid + s];
      __syncthreads();
    }
    if (tid == 0) ws_bias[q] = redm[0] / (float)B;
    __syncthreads();
  }
}

// ---------- K2: features (KT=4, explicit-carry counters) + fused row norm ----
template <int D>
__device__ __forceinline__ void run_feat(const float* xs,
                                         const float* __restrict__ kern,
                                         float b0, float b1, float b2,
                                         float* __restrict__ row, int K) {
  const int tid = threadIdx.x;
  const int wave = tid >> 6, lane = tid & 63;
  constexpr int L = IN_LEN - 8 * D;
  constexpr int NFULL = 31;   // pairs (t, t+64): max t+64 = 3967 < 4048 <= L
  constexpr int KT = 4;

  const int KPW = (K + 3) >> 2;
  const int kstart = wave * KPW;
  const int kend = (kstart + KPW < K) ? (kstart + KPW) : K;

  for (int k0 = kstart; k0 < kend; k0 += KT) {
    float w[KT][9];   // wave-uniform -> SGPRs
#pragma unroll
    for (int kk = 0; kk < KT; kk++) {
      const int kidx = (k0 + kk < K) ? (k0 + kk) : (K - 1);
      const bool ok = (k0 + kk) < kend;
      const float* wp = kern + (size_t)kidx * 9;
#pragma unroll
      for (int j = 0; j < 9; j++) w[kk][j] = ok ? wp[j] : 0.f;
    }
    unsigned c0[KT], c1[KT], c2[KT];
#pragma unroll
    for (int kk = 0; kk < KT; kk++) { c0[kk] = 0u; c1[kk] = 0u; c2[kk] = 0u; }
    unsigned long long ccA, ccB, ccC;  // three independent carry chains

#pragma unroll 1
    for (int p = 0; p < NFULL; ++p) {
      const int t = (p << 7) + lane;
      float tax[9], tay[9];
#pragma unroll
      for (int j = 0; j < 9; j++) {   // pairs -> ds_read2_b32 (offsets jD, jD+64)
        tax[j] = xs[t + j * D];
        tay[j] = xs[t + 64 + j * D];
      }
#pragma unroll
      for (int kk = 0; kk < KT; kk++) {
        float ca = 0.f, cb = 0.f;
#pragma unroll
        for (int j = 0; j < 9; j++) {
          ca = fmaf(w[kk][j], tax[j], ca);
          cb = fmaf(w[kk][j], tay[j], cb);
        }
        count2_gt_f32(c0[kk], ccA, b0, ca, cb);
        count2_gt_f32(c1[kk], ccB, b1, ca, cb);
        count2_gt_f32(c2[kk], ccC, b2, ca, cb);
      }
    }
    {  // tail pass p=31: t=3968+lane always < 4048 <= L; t+64 masked vs L
      const int t = (NFULL << 7) + lane;
      const bool v1 = (t + 64) < L;
      float tax[9], tay[9];
#pragma unroll
      for (int j = 0; j < 9; j++) {   // xs padded to IN_LEN+48, always in-bounds
        tax[j] = xs[t + j * D];
        tay[j] = xs[t + 64 + j * D];
      }
#pragma unroll
      for (int kk = 0; kk < KT; kk++) {
        float ca = 0.f, cb = 0.f;
#pragma unroll
        for (int j = 0; j < 9; j++) {
          ca = fmaf(w[kk][j], tax[j], ca);
          cb = fmaf(w[kk][j], tay[j], cb);
        }
        cb = v1 ? cb : -3.0e38f;   // below all thresholds -> not counted
        count2_gt_f32(c0[kk], ccA, b0, ca, cb);
        count2_gt_f32(c1[kk], ccB, b1, ca, cb);
        count2_gt_f32(c2[kk], ccC, b2, ca, cb);
      }
    }

    // ---- wave reduction (pack c0|c2: lane cnt <= 64, wave sum <= 4096) ----
#pragma unroll
    for (int kk = 0; kk < KT; kk++) {
      unsigned r0 = c0[kk] | (c2[kk] << 16);
      unsigned r1 = c1[kk];
#pragma unroll
      for (int off = 32; off > 0; off >>= 1) {
        r0 += (unsigned)__shfl_xor((int)r0, off);
        r1 += (unsigned)__shfl_xor((int)r1, off);
      }
      const int k = k0 + kk;
      if (lane == 0 && k < kend) {
        float* o = row + (size_t)k * 18 + (D - 1) * 3;
        o[0] = (float)(r0 & 0xFFFFu) / (float)L;
        o[1] = (float)r1 / (float)L;
        o[2] = (float)(r0 >> 16) / (float)L;
      }
    }
  }
}

__global__ __launch_bounds__(256, 8) void feat_norm_kernel(const float* __restrict__ x,
                                                           const float* __restrict__ kern,
                                                           unsigned char* __restrict__ ws,
                                                           float* __restrict__ out, int K) {
  __shared__ __align__(16) float xs[IN_LEN + 48];
  __shared__ float red[256];
  __shared__ unsigned lastflag;
  const int b = blockIdx.y, tid = threadIdx.x;
  const float* ws_bias = (const float*)(ws + WS_BIAS);
  unsigned* done = (unsigned*)(ws + WS_DONE);

  const float4* xg = (const float4*)(x + (size_t)b * IN_LEN);
  float4* xs4 = (float4*)xs;
  for (int i = tid; i < IN_LEN / 4; i += 256) xs4[i] = xg[i];
  if (tid < 48) xs[IN_LEN + tid] = 0.f;
  const float b0 = ws_bias[0], b1 = ws_bias[1], b2 = ws_bias[2];
  __syncthreads();

  float* row = out + (size_t)b * NFEAT;
  switch (blockIdx.x) {
    case 0: run_feat<1>(xs, kern, b0, b1, b2, row, K); break;
    case 1: run_feat<2>(xs, kern, b0, b1, b2, row, K); break;
    case 2: run_feat<3>(xs, kern, b0, b1, b2, row, K); break;
    case 3: run_feat<4>(xs, kern, b0, b1, b2, row, K); break;
    case 4: run_feat<5>(xs, kern, b0, b1, b2, row, K); break;
    case 5: run_feat<6>(xs, kern, b0, b1, b2, row, K); break;
  }

  // ---- publish this block's features; 6th block of the row normalizes ----
  __syncthreads();
  if (tid == 0) {
    __threadfence();
    unsigned old = __hip_atomic_fetch_add(&done[b], 1u, __ATOMIC_ACQ_REL, __HIP_MEMORY_SCOPE_AGENT);
    lastflag = (old == 5u) ? 1u : 0u;
  }
  __syncthreads();
  if (lastflag == 0u) return;
  __threadfence();

  const int F = K * 18;
  float acc = 0.f;
  for (int i = tid; i < F; i += 256) {
    float v = row[i];
    acc = fmaf(v, v, acc);
  }
  red[tid] = acc;
  __syncthreads();
  for (int s = 128; s > 0; s >>= 1) {
    if (tid < s) red[tid] += red[tid + s];
    __syncthreads();
  }
  const float inv = 1.0f / fmaxf(sqrtf(red[0]), 1e-12f);
  for (int i = tid; i < NFEAT; i += 256) {
    float v = (i < F) ? row[i] * inv : 0.f;
    row[i] = v;
  }
}

extern "C" void kernel_launch(void* const* d_in, const int* in_sizes, int n_in,
                              void* d_out, int out_size, void* d_ws, size_t ws_size,
                              hipStream_t stream) {
  const float* x = (const float*)d_in[0];
  const float* kern = (const float*)d_in[1];
  float* out = (float*)d_out;
  const int B = in_sizes[0] / IN_LEN;  // 256
  const int K = in_sizes[1] / 9;       // ~61 surviving kernels
  unsigned char* ws = (unsigned char*)d_ws;

  // zero the two counter regions (K1 counter + 256 row counters)
  hipMemsetAsync(ws, 0, 2048, stream);
  quantbias_kernel<<<B, 256, 0, stream>>>(x, kern, ws);
  dim3 g(6, B);
  feat_norm_kernel<<<g, 256, 0, stream>>>(x, kern, ws, out, K);
}

// Round 10
// 240.013 us; speedup vs baseline: 3.6830x; 1.5122x over previous
//
#include <hip/hip_runtime.h>
#include <stdint.h>

#define IN_LEN 4096
#define NFEAT  10000

// ---- workspace byte layout ----
#define WS_CNTA 0      // u32: K1 last-block counter
#define WS_Q    2048   // 768 f32: per-sample quantiles
#define WS_BIAS 8192   // 3 f32: biases

// ---------- round-4 count idioms (vcc carry, volatile) — measured 146 us ----------
// cnt += (val > thr)
__device__ __forceinline__ void count_gt_f32(unsigned& cnt, float thr, float val) {
  asm volatile("v_cmp_lt_f32 vcc, %1, %2\n\t"
               "v_addc_co_u32 %0, vcc, 0, %0, vcc"
               : "+v"(cnt)
               : "v"(thr), "v"(val)
               : "vcc");
}
// cnt += (key <= mid)   -- explicit sgpr carry (from the passing r8/9 quant)
__device__ __forceinline__ void count_le_u32(unsigned& cnt, unsigned long long& cc,
                                             unsigned mid, unsigned key) {
  asm("v_cmp_ge_u32 %[cc], %[m], %[k]\n\t"
      "v_addc_co_u32 %[c], %[cc], 0, %[c], %[cc]"
      : [c] "+v"(cnt), [cc] "=&s"(cc)
      : [m] "s"(mid), [k] "v"(key));
}

__device__ __forceinline__ unsigned key_of(float f) {
  unsigned u = __float_as_uint(f);
  return (u & 0x80000000u) ? ~u : (u | 0x80000000u);
}
__device__ __forceinline__ float key_inv(unsigned k) {
  unsigned u = (k & 0x80000000u) ? (k ^ 0x80000000u) : ~k;
  return __uint_as_float(u);
}

// ---------- K1: per-sample quantiles + fused last-block bias mean (passed r8/9) ----
__global__ __launch_bounds__(256) void quantbias_kernel(const float* __restrict__ x,
                                                        const float* __restrict__ kern,
                                                        unsigned char* __restrict__ ws) {
  const int b = blockIdx.x, tid = threadIdx.x;
  float* ws_q = (float*)(ws + WS_Q);
  float* ws_bias = (float*)(ws + WS_BIAS);
  unsigned* cntA = (unsigned*)(ws + WS_CNTA);

  __shared__ __align__(16) float xs[IN_LEN];
  __shared__ unsigned redc[2][3 * 4];
  __shared__ float redm[256];
  __shared__ unsigned lastflag;

  const float4* xg = (const float4*)(x + (size_t)b * IN_LEN);
  float4* xs4 = (float4*)xs;
  for (int i = tid; i < IN_LEN / 4; i += 256) xs4[i] = xg[i];

  float w[9];
#pragma unroll
  for (int j = 0; j < 9; j++) w[j] = kern[j];
  __syncthreads();

  const int L = IN_LEN - 8;
  unsigned keys[16];
#pragma unroll
  for (int i = 0; i < 16; i++) {
    int t = tid + (i << 8);
    if (t < L) {
      float c = 0.f;
#pragma unroll
      for (int j = 0; j < 9; j++) c = fmaf(w[j], xs[t + j], c);
      keys[i] = key_of(c);
    } else {
      keys[i] = 0xFFFFFFFFu;
    }
  }

  const int targ[6] = {1021, 1022, 2043, 2044, 3065, 3066};
  unsigned lo[6], hi[6];
#pragma unroll
  for (int q = 0; q < 6; q++) { lo[q] = 0u; hi[q] = 0xFFFFFFFFu; }

  const int wave = tid >> 6, lane = tid & 63;
  for (int it = 0; it < 32; ++it) {
    const int buf = it & 1;
    unsigned mid[6], cnt[6];
    unsigned long long ccq[3];
#pragma unroll
    for (int q = 0; q < 6; q++) { mid[q] = lo[q] + ((hi[q] - lo[q]) >> 1); cnt[q] = 0u; }
#pragma unroll
    for (int i = 0; i < 16; i++)
#pragma unroll
      for (int q = 0; q < 6; q++) count_le_u32(cnt[q], ccq[q >> 1], mid[q], keys[i]);
    unsigned r[3];
#pragma unroll
    for (int q = 0; q < 3; q++) r[q] = cnt[2 * q] | (cnt[2 * q + 1] << 16);
#pragma unroll
    for (int q = 0; q < 3; q++) {
#pragma unroll
      for (int off = 32; off > 0; off >>= 1) r[q] += (unsigned)__shfl_xor((int)r[q], off);
    }
    if (lane == 0) {
#pragma unroll
      for (int q = 0; q < 3; q++) redc[buf][q * 4 + wave] = r[q];
    }
    __syncthreads();
#pragma unroll
    for (int q = 0; q < 3; q++) {
      unsigned tot = redc[buf][q * 4 + 0] + redc[buf][q * 4 + 1] +
                     redc[buf][q * 4 + 2] + redc[buf][q * 4 + 3];
      unsigned t0 = tot & 0xFFFFu, t1 = tot >> 16;
      if (t0 >= (unsigned)(targ[2 * q] + 1)) hi[2 * q] = mid[2 * q]; else lo[2 * q] = mid[2 * q] + 1;
      if (t1 >= (unsigned)(targ[2 * q + 1] + 1)) hi[2 * q + 1] = mid[2 * q + 1]; else lo[2 * q + 1] = mid[2 * q + 1] + 1;
    }
  }

  if (tid == 0) {
    float v[6];
#pragma unroll
    for (int q = 0; q < 6; q++) v[q] = key_inv(lo[q]);
    ws_q[b * 3 + 0] = v[0] + 0.75f * (v[1] - v[0]);
    ws_q[b * 3 + 1] = v[2] + 0.5f  * (v[3] - v[2]);
    ws_q[b * 3 + 2] = v[4] + 0.25f * (v[5] - v[4]);
  }

  __syncthreads();
  if (tid == 0) {
    __threadfence();
    unsigned old = __hip_atomic_fetch_add(cntA, 1u, __ATOMIC_ACQ_REL, __HIP_MEMORY_SCOPE_AGENT);
    lastflag = (old == gridDim.x - 1) ? 1u : 0u;
  }
  __syncthreads();
  if (lastflag == 0u) return;
  __threadfence();
  const int B = gridDim.x;
  for (int q = 0; q < 3; q++) {
    float v = 0.f;
    for (int i = tid; i < B; i += 256) v += ws_q[i * 3 + q];
    redm[tid] = v;
    __syncthreads();
    for (int s = 128; s > 0; s >>= 1) {
      if (tid < s) redm[tid] += redm[tid + s];
      __syncthreads();
    }
    if (tid == 0) ws_bias[q] = redm[0] / (float)B;
    __syncthreads();
  }
}

// ---------- K2: EXACT round-4 feat kernel (measured 146.3 us) ----------
template <int D>
__device__ __forceinline__ void run_feat(const float* xs,
                                         const float* __restrict__ kern,
                                         float b0, float b1, float b2,
                                         float* __restrict__ out, int K, int b) {
  const int tid = threadIdx.x;
  const int wave = tid >> 6, lane = tid & 63;
  constexpr int L = IN_LEN - 8 * D;
  constexpr int NFULL = 31;        // 31 full passes of 128 positions per wave
  constexpr int KT = 8;

  const int KPW = (K + 3) >> 2;    // kernels per wave (16 for K=61)
  const int kstart = wave * KPW;
  const int kend = (kstart + KPW < K) ? (kstart + KPW) : K;

  for (int k0 = kstart; k0 < kend; k0 += KT) {
    float w[KT][9];
#pragma unroll
    for (int kk = 0; kk < KT; kk++) {
      const int kidx = (k0 + kk < K) ? (k0 + kk) : (K - 1);
      const bool ok = (k0 + kk) < kend;
      const float* wp = kern + (size_t)kidx * 9;
#pragma unroll
      for (int j = 0; j < 9; j++) w[kk][j] = ok ? wp[j] : 0.f;
    }
    unsigned c0[KT], c1[KT], c2[KT];
#pragma unroll
    for (int kk = 0; kk < KT; kk++) { c0[kk] = 0u; c1[kk] = 0u; c2[kk] = 0u; }

#pragma unroll 1
    for (int p = 0; p < NFULL; ++p) {
      const int t = (p << 7) + lane;
      float tax[9], tay[9];
#pragma unroll
      for (int j = 0; j < 9; j++) {       // pairs -> ds_read2_b32 (offsets jD, jD+64)
        tax[j] = xs[t + j * D];
        tay[j] = xs[t + 64 + j * D];
      }
#pragma unroll
      for (int kk = 0; kk < KT; kk++) {
        float ca = 0.f, cb = 0.f;
#pragma unroll
        for (int j = 0; j < 9; j++) {
          ca = fmaf(w[kk][j], tax[j], ca);
          cb = fmaf(w[kk][j], tay[j], cb);
        }
        count_gt_f32(c0[kk], b0, ca); count_gt_f32(c0[kk], b0, cb);
        count_gt_f32(c1[kk], b1, ca); count_gt_f32(c1[kk], b1, cb);
        count_gt_f32(c2[kk], b2, ca); count_gt_f32(c2[kk], b2, cb);
      }
    }
    {  // masked tail pass
      const int t = (NFULL << 7) + lane;
      const bool v0 = t < L, v1 = (t + 64) < L;
      float tax[9], tay[9];
#pragma unroll
      for (int j = 0; j < 9; j++) {       // xs padded to IN_LEN+48, always safe
        tax[j] = xs[t + j * D];
        tay[j] = xs[t + 64 + j * D];
      }
#pragma unroll
      for (int kk = 0; kk < KT; kk++) {
        float ca = 0.f, cb = 0.f;
#pragma unroll
        for (int j = 0; j < 9; j++) {
          ca = fmaf(w[kk][j], tax[j], ca);
          cb = fmaf(w[kk][j], tay[j], cb);
        }
        ca = v0 ? ca : -3.0e38f;
        cb = v1 ? cb : -3.0e38f;
        count_gt_f32(c0[kk], b0, ca); count_gt_f32(c0[kk], b0, cb);
        count_gt_f32(c1[kk], b1, ca); count_gt_f32(c1[kk], b1, cb);
        count_gt_f32(c2[kk], b2, ca); count_gt_f32(c2[kk], b2, cb);
      }
    }

#pragma unroll
    for (int kk = 0; kk < KT; kk++) {
      unsigned r0 = c0[kk] | (c2[kk] << 16);
      unsigned r1 = c1[kk];
#pragma unroll
      for (int off = 32; off > 0; off >>= 1) {
        r0 += (unsigned)__shfl_xor((int)r0, off);
        r1 += (unsigned)__shfl_xor((int)r1, off);
      }
      const int k = k0 + kk;
      if (lane == 0 && k < kend) {
        float* o = out + (size_t)b * NFEAT + (size_t)k * 18 + (D - 1) * 3;
        o[0] = (float)(r0 & 0xFFFFu) / (float)L;
        o[1] = (float)r1 / (float)L;
        o[2] = (float)(r0 >> 16) / (float)L;
      }
    }
  }
}

__global__ __launch_bounds__(256) void feat_kernel(const float* __restrict__ x,
                                                   const float* __restrict__ kern,
                                                   const unsigned char* __restrict__ ws,
                                                   float* __restrict__ out, int K) {
  __shared__ __align__(16) float xs[IN_LEN + 48];
  const int b = blockIdx.y, tid = threadIdx.x;
  const float* ws_bias = (const float*)(ws + WS_BIAS);

  const float4* xg = (const float4*)(x + (size_t)b * IN_LEN);
  float4* xs4 = (float4*)xs;
  for (int i = tid; i < IN_LEN / 4; i += 256) xs4[i] = xg[i];
  if (tid < 48) xs[IN_LEN + tid] = 0.f;
  const float b0 = ws_bias[0], b1 = ws_bias[1], b2 = ws_bias[2];
  __syncthreads();

  switch (blockIdx.x) {
    case 0: run_feat<1>(xs, kern, b0, b1, b2, out, K, b); break;
    case 1: run_feat<2>(xs, kern, b0, b1, b2, out, K, b); break;
    case 2: run_feat<3>(xs, kern, b0, b1, b2, out, K, b); break;
    case 3: run_feat<4>(xs, kern, b0, b1, b2, out, K, b); break;
    case 4: run_feat<5>(xs, kern, b0, b1, b2, out, K, b); break;
    case 5: run_feat<6>(xs, kern, b0, b1, b2, out, K, b); break;
  }
}

// ---------- K3: row L2 norm over first F columns + zero the tail (passed r5) ----
__global__ __launch_bounds__(256) void norm_kernel(float* __restrict__ out, int F) {
  const int b = blockIdx.x, tid = threadIdx.x;
  __shared__ float red[256];
  float* row = out + (size_t)b * NFEAT;
  float acc = 0.f;
  for (int i = tid; i < F; i += 256) {
    float v = row[i];
    acc = fmaf(v, v, acc);
  }
  red[tid] = acc;
  __syncthreads();
  for (int s = 128; s > 0; s >>= 1) {
    if (tid < s) red[tid] += red[tid + s];
    __syncthreads();
  }
  const float inv = 1.0f / fmaxf(sqrtf(red[0]), 1e-12f);
  for (int i = tid; i < NFEAT; i += 256) {
    float v = (i < F) ? row[i] * inv : 0.f;
    row[i] = v;
  }
}

extern "C" void kernel_launch(void* const* d_in, const int* in_sizes, int n_in,
                              void* d_out, int out_size, void* d_ws, size_t ws_size,
                              hipStream_t stream) {
  const float* x = (const float*)d_in[0];
  const float* kern = (const float*)d_in[1];
  float* out = (float*)d_out;
  const int B = in_sizes[0] / IN_LEN;  // 256
  const int K = in_sizes[1] / 9;       // ~61 surviving kernels
  unsigned char* ws = (unsigned char*)d_ws;

  hipMemsetAsync(ws, 0, 2048, stream);                 // K1 last-block counter
  quantbias_kernel<<<B, 256, 0, stream>>>(x, kern, ws);
  dim3 g(6, B);
  feat_kernel<<<g, 256, 0, stream>>>(x, kern, ws, out, K);
  norm_kernel<<<B, 256, 0, stream>>>(out, K * 18);
}